// Round 4
// baseline (207.812 us; speedup 1.0000x reference)
//
#include <hip/hip_runtime.h>
#include <hip/hip_bf16.h>
#include <math.h>

// ---------------- problem constants ----------------
#define M 8192
#define N 16384
#define D 64
#define ZC 58.81206612509905f        // 32*log(2*pi), h=1
#define B0 24.0f                     // exp2-domain bias (headroom; u<=0)
#define LOG2E 1.4426950408889634f
#define HL2E 0.7213475204444817f     // 0.5*log2(e)
#define LN2 0.6931471805599453f

#define PCH 32
#define NCHK (N / PCH)               // 512 train cols per block

typedef short v8bf __attribute__((ext_vector_type(8)));   // 8 bf16 (4 VGPRs)
typedef float v16f __attribute__((ext_vector_type(16)));

// ws layout (bytes)
#define B_AU2  0                        // 8192 f32  (32 KB)
#define B_LW2  32768                    // 16384 f32 (64 KB)
#define B_PART 98304                    // 32*8192 f32 (1 MB), [chunk][m]
#define B_TB   1146880                  // 8192*64 bf16 (1 MB)
#define B_TR   2195456                  // 16384*64 bf16 (2 MB)

// Fused prep: blocks 0..255 convert testX -> bf16(log2e*x) + au2;
// blocks 256..767 convert trainX -> bf16 + lw2 = log2(w) - hl2e*r2 + B0.
__global__ __launch_bounds__(256) void gk_prep(const float* __restrict__ testX,
                                               const float* __restrict__ trainX,
                                               const float* __restrict__ sw,
                                               __hip_bfloat16* __restrict__ tb,
                                               __hip_bfloat16* __restrict__ rb,
                                               float* __restrict__ au2,
                                               float* __restrict__ lw2) {
    const int tid = threadIdx.x;
    const int e = tid & 7;
    if (blockIdx.x < M / 32) {
        const int row = blockIdx.x * 32 + (tid >> 3);
        const float4* p = reinterpret_cast<const float4*>(testX + (size_t)row * D + e * 8);
        float4 v0 = p[0], v1 = p[1];
        float t2 = v0.x * v0.x + v0.y * v0.y + v0.z * v0.z + v0.w * v0.w
                 + v1.x * v1.x + v1.y * v1.y + v1.z * v1.z + v1.w * v1.w;
        t2 += __shfl_xor(t2, 1, 64);
        t2 += __shfl_xor(t2, 2, 64);
        t2 += __shfl_xor(t2, 4, 64);
        if (e == 0) au2[row] = -HL2E * t2;
        union { __hip_bfloat16 h[8]; uint4 u; } cv;
        cv.h[0] = __float2bfloat16(v0.x * LOG2E);
        cv.h[1] = __float2bfloat16(v0.y * LOG2E);
        cv.h[2] = __float2bfloat16(v0.z * LOG2E);
        cv.h[3] = __float2bfloat16(v0.w * LOG2E);
        cv.h[4] = __float2bfloat16(v1.x * LOG2E);
        cv.h[5] = __float2bfloat16(v1.y * LOG2E);
        cv.h[6] = __float2bfloat16(v1.z * LOG2E);
        cv.h[7] = __float2bfloat16(v1.w * LOG2E);
        *reinterpret_cast<uint4*>(tb + (size_t)row * D + e * 8) = cv.u;
    } else {
        const int row = (blockIdx.x - M / 32) * 32 + (tid >> 3);
        const float4* p = reinterpret_cast<const float4*>(trainX + (size_t)row * D + e * 8);
        float4 v0 = p[0], v1 = p[1];
        float r2 = v0.x * v0.x + v0.y * v0.y + v0.z * v0.z + v0.w * v0.w
                 + v1.x * v1.x + v1.y * v1.y + v1.z * v1.z + v1.w * v1.w;
        r2 += __shfl_xor(r2, 1, 64);
        r2 += __shfl_xor(r2, 2, 64);
        r2 += __shfl_xor(r2, 4, 64);
        if (e == 0) lw2[row] = __builtin_amdgcn_logf(sw[row]) - HL2E * r2 + B0;
        union { __hip_bfloat16 h[8]; uint4 u; } cv;
        cv.h[0] = __float2bfloat16(v0.x);
        cv.h[1] = __float2bfloat16(v0.y);
        cv.h[2] = __float2bfloat16(v0.z);
        cv.h[3] = __float2bfloat16(v0.w);
        cv.h[4] = __float2bfloat16(v1.x);
        cv.h[5] = __float2bfloat16(v1.y);
        cv.h[6] = __float2bfloat16(v1.z);
        cv.h[7] = __float2bfloat16(v1.w);
        *reinterpret_cast<uint4*>(rb + (size_t)row * D + e * 8) = cv.u;
    }
}

// Main: 128 test rows x 512 train cols per block (grid 2048 = 8 blocks/CU).
// A-fragments direct from global (no A LDS); B single-buffer LDS 16 KB
// xor-swizzled; bias in MFMA C operand; epilogue = exp2 + add.
__global__ __launch_bounds__(256, 6) void gk_main(const __hip_bfloat16* __restrict__ ta,
                                                  const __hip_bfloat16* __restrict__ tr,
                                                  const float* __restrict__ lw2,
                                                  float* __restrict__ part) {
    __shared__ __align__(16) char smem[17408];   // Bs 16K | Lw 512B (red: 16.9K)
    const int tid = threadIdx.x;
    const int w = tid >> 6;
    const int lane = tid & 63;
    const int c = lane & 31;
    const int h = lane >> 5;
    const int rl = lane >> 3;      // staging row-in-group 0..7
    const int kb = lane & 7;       // staging 16B k-chunk 0..7

    // XCD swizzle: xcd = bid&7 owns chunks 4x..4x+3 (2048 train rows, 256 KB bf16)
    const int bid = blockIdx.x;
    const int xcd = bid & 7;
    const int j = bid >> 3;
    const int chunk = xcd * 4 + (j & 3);
    const int m0 = (j >> 2) * 128;
    const int n0 = chunk * NCHK;

    // A fragments once per block, straight from global bf16
    const __hip_bfloat16* arow = ta + (size_t)(m0 + w * 32 + c) * D;
    v8bf af[4];
#pragma unroll
    for (int t = 0; t < 4; ++t)
        af[t] = *reinterpret_cast<const v8bf*>(arow + (2 * t + h) * 8);

    float srun[16];
#pragma unroll
    for (int r = 0; r < 16; ++r) srun[r] = 0.f;

    char* Bs = smem;
    float* Lw = reinterpret_cast<float*>(smem + 16384);

    for (int tile = 0; tile < NCHK / 128; ++tile) {   // 4 tiles
        __syncthreads();
        const int nt0 = n0 + tile * 128;
#pragma unroll
        for (int i = 0; i < 4; ++i) {
            int rr = w * 32 + i * 8 + rl;
            uint4 v = *reinterpret_cast<const uint4*>(tr + (size_t)(nt0 + rr) * D + kb * 8);
            *reinterpret_cast<uint4*>(Bs + kb * 2048 + ((rr ^ kb) * 16)) = v;
        }
        if (tid < 128) Lw[tid] = lw2[nt0 + tid];
        __syncthreads();

#pragma unroll
        for (int s = 0; s < 4; ++s) {
            float lwv = Lw[s * 32 + c];
            v16f acc;
#pragma unroll
            for (int r = 0; r < 16; ++r) acc[r] = lwv;   // bias = MFMA C operand
#pragma unroll
            for (int t = 0; t < 4; ++t) {
                int kk = 2 * t + h;
                v8bf bf = *reinterpret_cast<const v8bf*>(Bs + kk * 2048 + (((s * 32 + c) ^ kk) * 16));
                acc = __builtin_amdgcn_mfma_f32_32x32x16_bf16(af[t], bf, acc, 0, 0, 0);
            }
#pragma unroll
            for (int r = 0; r < 16; ++r)
                srun[r] += __builtin_amdgcn_exp2f(acc[r]);
        }
    }

    // ---- cross-lane row sum (cols live across 32 lanes) ----
    __syncthreads();
    float* red = reinterpret_cast<float*>(smem);   // 128 x 33 f32 (16896 B)
#pragma unroll
    for (int r = 0; r < 16; ++r) {
        int rowl = (r & 3) + 8 * (r >> 2) + 4 * h;
        red[(w * 32 + rowl) * 33 + c] = srun[r];
    }
    __syncthreads();
    if (tid < 128) {
        float G = 0.f;
#pragma unroll
        for (int c2 = 0; c2 < 32; ++c2) G += red[tid * 33 + c2];
        part[(size_t)chunk * M + m0 + tid] = G;   // [chunk][m] coalesced
    }
}

__global__ __launch_bounds__(256) void gk_merge(const float* __restrict__ part,
                                                const float* __restrict__ au2,
                                                const float* __restrict__ sw,
                                                float* __restrict__ out) {
    __shared__ float red[256];
    const int tid = threadIdx.x;
    // W = sum(sw), recomputed per block (64 KB, L2-resident, fully parallel)
    float s = 0.f;
    const float4* p4 = reinterpret_cast<const float4*>(sw);
    for (int i = tid; i < N / 4; i += 256) {
        float4 v = p4[i];
        s += v.x + v.y + v.z + v.w;
    }
    red[tid] = s;
    __syncthreads();
    for (int off = 128; off > 0; off >>= 1) {
        if (tid < off) red[tid] += red[tid + off];
        __syncthreads();
    }
    const float W = red[0];

    const int r = blockIdx.x * 256 + tid;
    float G = 0.f;
#pragma unroll
    for (int p = 0; p < PCH; ++p) G += part[(size_t)p * M + r];
    out[r] = LN2 * (au2[r] + __builtin_amdgcn_logf(fmaxf(G, 1e-30f)) - B0
                   - __builtin_amdgcn_logf(W)) - ZC;
}

extern "C" void kernel_launch(void* const* d_in, const int* in_sizes, int n_in,
                              void* d_out, int out_size, void* d_ws, size_t ws_size,
                              hipStream_t stream) {
    const float* testX  = (const float*)d_in[0];   // [8192, 64]
    const float* trainX = (const float*)d_in[1];   // [16384, 64]
    const float* sw     = (const float*)d_in[2];   // [16384]
    float* out = (float*)d_out;                    // [8192]
    char* wsb = (char*)d_ws;

    float* au2  = (float*)(wsb + B_AU2);
    float* lw2  = (float*)(wsb + B_LW2);
    float* part = (float*)(wsb + B_PART);
    __hip_bfloat16* tb = (__hip_bfloat16*)(wsb + B_TB);
    __hip_bfloat16* rb = (__hip_bfloat16*)(wsb + B_TR);

    gk_prep<<<M / 32 + N / 32, 256, 0, stream>>>(testX, trainX, sw, tb, rb, au2, lw2);
    gk_main<<<(M / 128) * PCH, 256, 0, stream>>>(tb, rb, lw2, part);
    gk_merge<<<M / 256, 256, 0, stream>>>(part, au2, sw, out);
}

// Round 5
// 101.482 us; speedup vs baseline: 2.0478x; 2.0478x over previous
//
#include <hip/hip_runtime.h>
#include <hip/hip_bf16.h>
#include <math.h>

// ---------------- problem constants ----------------
#define M 8192
#define N 16384
#define D 64
#define ZC 58.81206612509905f        // 32*log(2*pi), h=1
#define B0 24.0f                     // exp2-domain bias (headroom; u<=0)
#define LOG2E 1.4426950408889634f
#define HL2E 0.7213475204444817f     // 0.5*log2(e)
#define LN2 0.6931471805599453f

#define PCH 32
#define NCHK (N / PCH)               // 512 train cols per block

typedef short v8bf __attribute__((ext_vector_type(8)));   // 8 bf16 (4 VGPRs)
typedef float v16f __attribute__((ext_vector_type(16)));

// ws layout (bytes)
#define B_AU2  0                        // 8192 f32  (32 KB)
#define B_LW2  32768                    // 16384 f32 (64 KB)
#define B_PART 98304                    // 32*8192 f32 (1 MB), [chunk][m]
#define B_TB   1146880                  // 8192*64 bf16 (1 MB)
#define B_TR   2195456                  // 16384*64 bf16 (2 MB)

// Fused prep: blocks 0..255 convert testX -> bf16(log2e*x) + au2;
// blocks 256..767 convert trainX -> bf16 + lw2 = log2(w) - hl2e*r2 + B0.
__global__ __launch_bounds__(256) void gk_prep(const float* __restrict__ testX,
                                               const float* __restrict__ trainX,
                                               const float* __restrict__ sw,
                                               __hip_bfloat16* __restrict__ tb,
                                               __hip_bfloat16* __restrict__ rb,
                                               float* __restrict__ au2,
                                               float* __restrict__ lw2) {
    const int tid = threadIdx.x;
    const int e = tid & 7;
    if (blockIdx.x < M / 32) {
        const int row = blockIdx.x * 32 + (tid >> 3);
        const float4* p = reinterpret_cast<const float4*>(testX + (size_t)row * D + e * 8);
        float4 v0 = p[0], v1 = p[1];
        float t2 = v0.x * v0.x + v0.y * v0.y + v0.z * v0.z + v0.w * v0.w
                 + v1.x * v1.x + v1.y * v1.y + v1.z * v1.z + v1.w * v1.w;
        t2 += __shfl_xor(t2, 1, 64);
        t2 += __shfl_xor(t2, 2, 64);
        t2 += __shfl_xor(t2, 4, 64);
        if (e == 0) au2[row] = -HL2E * t2;
        union { __hip_bfloat16 h[8]; uint4 u; } cv;
        cv.h[0] = __float2bfloat16(v0.x * LOG2E);
        cv.h[1] = __float2bfloat16(v0.y * LOG2E);
        cv.h[2] = __float2bfloat16(v0.z * LOG2E);
        cv.h[3] = __float2bfloat16(v0.w * LOG2E);
        cv.h[4] = __float2bfloat16(v1.x * LOG2E);
        cv.h[5] = __float2bfloat16(v1.y * LOG2E);
        cv.h[6] = __float2bfloat16(v1.z * LOG2E);
        cv.h[7] = __float2bfloat16(v1.w * LOG2E);
        *reinterpret_cast<uint4*>(tb + (size_t)row * D + e * 8) = cv.u;
    } else {
        const int row = (blockIdx.x - M / 32) * 32 + (tid >> 3);
        const float4* p = reinterpret_cast<const float4*>(trainX + (size_t)row * D + e * 8);
        float4 v0 = p[0], v1 = p[1];
        float r2 = v0.x * v0.x + v0.y * v0.y + v0.z * v0.z + v0.w * v0.w
                 + v1.x * v1.x + v1.y * v1.y + v1.z * v1.z + v1.w * v1.w;
        r2 += __shfl_xor(r2, 1, 64);
        r2 += __shfl_xor(r2, 2, 64);
        r2 += __shfl_xor(r2, 4, 64);
        if (e == 0) lw2[row] = __builtin_amdgcn_logf(sw[row]) - HL2E * r2 + B0;
        union { __hip_bfloat16 h[8]; uint4 u; } cv;
        cv.h[0] = __float2bfloat16(v0.x);
        cv.h[1] = __float2bfloat16(v0.y);
        cv.h[2] = __float2bfloat16(v0.z);
        cv.h[3] = __float2bfloat16(v0.w);
        cv.h[4] = __float2bfloat16(v1.x);
        cv.h[5] = __float2bfloat16(v1.y);
        cv.h[6] = __float2bfloat16(v1.z);
        cv.h[7] = __float2bfloat16(v1.w);
        *reinterpret_cast<uint4*>(rb + (size_t)row * D + e * 8) = cv.u;
    }
}

// Main: 128 test rows x 512 train cols per block (grid 2048 = 8 blocks/CU by
// grid; 4 resident by VGPR). A-fragments direct from global (no A LDS);
// B single-buffer LDS 16 KB xor-swizzled; bias in MFMA C operand;
// epilogue = exp2 + add.
// launch_bounds(256,4): 128-VGPR cap. (256,6) in round 4 forced a 40-VGPR
// allocation -> accumulator spill -> 264/281 MB scratch traffic, 3x slower.
__global__ __launch_bounds__(256, 4) void gk_main(const __hip_bfloat16* __restrict__ ta,
                                                  const __hip_bfloat16* __restrict__ tr,
                                                  const float* __restrict__ lw2,
                                                  float* __restrict__ part) {
    __shared__ __align__(16) char smem[17408];   // Bs 16K | Lw 512B (red reuse: 16.9K)
    const int tid = threadIdx.x;
    const int w = tid >> 6;
    const int lane = tid & 63;
    const int c = lane & 31;
    const int h = lane >> 5;
    const int rl = lane >> 3;      // staging row-in-group 0..7
    const int kb = lane & 7;       // staging 16B k-chunk 0..7

    // XCD swizzle: xcd = bid&7 owns chunks 4x..4x+3 (2048 train rows, 256 KB bf16)
    const int bid = blockIdx.x;
    const int xcd = bid & 7;
    const int j = bid >> 3;
    const int chunk = xcd * 4 + (j & 3);
    const int m0 = (j >> 2) * 128;
    const int n0 = chunk * NCHK;

    // A fragments once per block, straight from global bf16
    const __hip_bfloat16* arow = ta + (size_t)(m0 + w * 32 + c) * D;
    v8bf af[4];
#pragma unroll
    for (int t = 0; t < 4; ++t)
        af[t] = *reinterpret_cast<const v8bf*>(arow + (2 * t + h) * 8);

    float srun[16];
#pragma unroll
    for (int r = 0; r < 16; ++r) srun[r] = 0.f;

    char* Bs = smem;
    float* Lw = reinterpret_cast<float*>(smem + 16384);

    for (int tile = 0; tile < NCHK / 128; ++tile) {   // 4 tiles
        __syncthreads();
        const int nt0 = n0 + tile * 128;
#pragma unroll
        for (int i = 0; i < 4; ++i) {
            int rr = w * 32 + i * 8 + rl;
            uint4 v = *reinterpret_cast<const uint4*>(tr + (size_t)(nt0 + rr) * D + kb * 8);
            *reinterpret_cast<uint4*>(Bs + kb * 2048 + ((rr ^ kb) * 16)) = v;
        }
        if (tid < 128) Lw[tid] = lw2[nt0 + tid];
        __syncthreads();

#pragma unroll
        for (int s = 0; s < 4; ++s) {
            float lwv = Lw[s * 32 + c];
            v16f acc;
#pragma unroll
            for (int r = 0; r < 16; ++r) acc[r] = lwv;   // bias = MFMA C operand
#pragma unroll
            for (int t = 0; t < 4; ++t) {
                int kk = 2 * t + h;
                v8bf bf = *reinterpret_cast<const v8bf*>(Bs + kk * 2048 + (((s * 32 + c) ^ kk) * 16));
                acc = __builtin_amdgcn_mfma_f32_32x32x16_bf16(af[t], bf, acc, 0, 0, 0);
            }
#pragma unroll
            for (int r = 0; r < 16; ++r)
                srun[r] += __builtin_amdgcn_exp2f(acc[r]);
        }
    }

    // ---- cross-lane row sum (cols live across 32 lanes) ----
    __syncthreads();
    float* red = reinterpret_cast<float*>(smem);   // 128 x 33 f32 (16896 B)
#pragma unroll
    for (int r = 0; r < 16; ++r) {
        int rowl = (r & 3) + 8 * (r >> 2) + 4 * h;
        red[(w * 32 + rowl) * 33 + c] = srun[r];
    }
    __syncthreads();
    if (tid < 128) {
        float G = 0.f;
#pragma unroll
        for (int c2 = 0; c2 < 32; ++c2) G += red[tid * 33 + c2];
        part[(size_t)chunk * M + m0 + tid] = G;   // [chunk][m] coalesced
    }
}

__global__ __launch_bounds__(256) void gk_merge(const float* __restrict__ part,
                                                const float* __restrict__ au2,
                                                const float* __restrict__ sw,
                                                float* __restrict__ out) {
    __shared__ float red[256];
    const int tid = threadIdx.x;
    // W = sum(sw), recomputed per block (64 KB, L2-resident, fully parallel)
    float s = 0.f;
    const float4* p4 = reinterpret_cast<const float4*>(sw);
    for (int i = tid; i < N / 4; i += 256) {
        float4 v = p4[i];
        s += v.x + v.y + v.z + v.w;
    }
    red[tid] = s;
    __syncthreads();
    for (int off = 128; off > 0; off >>= 1) {
        if (tid < off) red[tid] += red[tid + off];
        __syncthreads();
    }
    const float W = red[0];

    const int r = blockIdx.x * 256 + tid;
    float G = 0.f;
#pragma unroll
    for (int p = 0; p < PCH; ++p) G += part[(size_t)p * M + r];
    out[r] = LN2 * (au2[r] + __builtin_amdgcn_logf(fmaxf(G, 1e-30f)) - B0
                   - __builtin_amdgcn_logf(W)) - ZC;
}

extern "C" void kernel_launch(void* const* d_in, const int* in_sizes, int n_in,
                              void* d_out, int out_size, void* d_ws, size_t ws_size,
                              hipStream_t stream) {
    const float* testX  = (const float*)d_in[0];   // [8192, 64]
    const float* trainX = (const float*)d_in[1];   // [16384, 64]
    const float* sw     = (const float*)d_in[2];   // [16384]
    float* out = (float*)d_out;                    // [8192]
    char* wsb = (char*)d_ws;

    float* au2  = (float*)(wsb + B_AU2);
    float* lw2  = (float*)(wsb + B_LW2);
    float* part = (float*)(wsb + B_PART);
    __hip_bfloat16* tb = (__hip_bfloat16*)(wsb + B_TB);
    __hip_bfloat16* rb = (__hip_bfloat16*)(wsb + B_TR);

    gk_prep<<<M / 32 + N / 32, 256, 0, stream>>>(testX, trainX, sw, tb, rb, au2, lw2);
    gk_main<<<(M / 128) * PCH, 256, 0, stream>>>(tb, rb, lw2, part);
    gk_merge<<<M / 256, 256, 0, stream>>>(part, au2, sw, out);
}